// Round 12
// baseline (1412.825 us; speedup 1.0000x reference)
//
#include <hip/hip_runtime.h>
#include <hip/hip_bf16.h>
#include <math.h>

#define BB 4
#define SEQ 512
#define TGT 256
#define DM 512
#define FFD 2048
#define NH 8
#define HD 64
#define NL 6

typedef unsigned short u16;
typedef __attribute__((ext_vector_type(4))) float f4;
typedef __attribute__((ext_vector_type(4))) unsigned short us4;
typedef __attribute__((ext_vector_type(8))) unsigned short us8;
typedef __attribute__((ext_vector_type(8))) short s8;

__device__ inline u16 f2b(float f) {
    __hip_bfloat16 h = __float2bfloat16(f);
    return *reinterpret_cast<u16*>(&h);
}
__device__ inline float b2f(u16 u) {
    unsigned int x = ((unsigned int)u) << 16;
    float f;
    __builtin_memcpy(&f, &x, 4);
    return f;
}
__device__ inline us4 cvt4(f4 v) {
    us4 u;
    u.x = f2b(v.x); u.y = f2b(v.y); u.z = f2b(v.z); u.w = f2b(v.w);
    return u;
}

// ---------------- batched fp32 -> bf16 cast, 8 elems/thread, nontemporal ----------------
struct CastSegs {
    const float* src[24];
    u16* dst[24];
    int cum[25];   // cumulative n8 (groups of 8 elements)
    int nseg;
};

__global__ __launch_bounds__(256) void castseg_k(CastSegs cs)
{
    int i = blockIdx.x * blockDim.x + threadIdx.x;
    if (i >= cs.cum[cs.nseg]) return;
    int s = 0;
    while (i >= cs.cum[s + 1]) s++;
    int local = i - cs.cum[s];
    const f4* sp = (const f4*)cs.src[s] + (size_t)local * 2;
    f4 lo = __builtin_nontemporal_load(sp);
    f4 hi = __builtin_nontemporal_load(sp + 1);
    us4 ul = cvt4(lo), uh = cvt4(hi);
    us8 o;
#pragma unroll
    for (int e = 0; e < 4; e++) { o[e] = ul[e]; o[e + 4] = uh[e]; }
    __builtin_nontemporal_store(o, (us8*)cs.dst[s] + local);
}

// ---------------- stack decoder cross-attn KV biases: [6][1024] fp32 ----------------
__global__ void kvbias_k(const float* __restrict__ dec_ca_b, float* __restrict__ out)
{
    int idx = blockIdx.x * blockDim.x + threadIdx.x;
    if (idx >= NL * 2 * DM) return;
    int layer = idx >> 10, j = idx & 1023;
    out[idx] = dec_ca_b[layer * 3 * DM + DM + j];
}

// ============ MFMA GEMM, bf16, BMx64 tile, BK=64, double-buffered LDS ============
// PE: 0 none, 1 encoder sinusoidal pe, 2 decoder pe row 0
template <int RELU, int OUTF32, int BM, int PE>
__global__ __launch_bounds__(256) void mgemm_k(
    const u16* __restrict__ A, const u16* __restrict__ W,
    const float* __restrict__ bias, const u16* __restrict__ resid,
    void* __restrict__ Cv, int M, int N, int K, float alpha)
{
    constexpr int MI = BM / 32;
    __shared__ u16 As[2][BM][72];
    __shared__ u16 Bs[2][64][72];
    const int bm = blockIdx.y * BM, bn = blockIdx.x * 64;
    const int tid = threadIdx.x;
    const int wave = tid >> 6, lane = tid & 63;
    const int wr = (wave >> 1) * (BM / 2), wc = (wave & 1) * 32;
    const int lm = lane & 15, quad = lane >> 4;
    const int sbr = tid >> 2, sbc = (tid & 3) * 16;
    const int sar = (BM == 64) ? (tid >> 2) : (tid >> 3);
    const int sac = (BM == 64) ? ((tid & 3) * 16) : ((tid & 7) * 8);

    const u16* Arow = A + (size_t)(bm + sar) * K + sac;
    const u16* Wrow = W + (size_t)(bn + sbr) * K + sbc;

    us8 a0 = *(const us8*)(Arow);
    us8 a1;
    if (BM == 64) a1 = *(const us8*)(Arow + 8);
    us8 b0 = *(const us8*)(Wrow);
    us8 b1 = *(const us8*)(Wrow + 8);

    f4 acc[MI][2];
#pragma unroll
    for (int i = 0; i < MI; i++)
#pragma unroll
        for (int j = 0; j < 2; j++) acc[i][j] = (f4)(0.f);

    const int nk = K >> 6;
    *(us8*)&As[0][sar][sac] = a0;
    if (BM == 64) *(us8*)&As[0][sar][sac + 8] = a1;
    *(us8*)&Bs[0][sbr][sbc] = b0;
    *(us8*)&Bs[0][sbr][sbc + 8] = b1;
    __syncthreads();

    for (int t = 0; t < nk; t++) {
        const int cb = t & 1;
        if (t + 1 < nk) {
            int off = (t + 1) << 6;
            a0 = *(const us8*)(Arow + off);
            if (BM == 64) a1 = *(const us8*)(Arow + off + 8);
            b0 = *(const us8*)(Wrow + off);
            b1 = *(const us8*)(Wrow + off + 8);
        }
#pragma unroll
        for (int ks = 0; ks < 2; ks++) {
            s8 af[MI], bfr[2];
#pragma unroll
            for (int i = 0; i < MI; i++) af[i] = *(const s8*)&As[cb][wr + i * 16 + lm][ks * 32 + quad * 8];
#pragma unroll
            for (int j = 0; j < 2; j++) bfr[j] = *(const s8*)&Bs[cb][wc + j * 16 + lm][ks * 32 + quad * 8];
#pragma unroll
            for (int i = 0; i < MI; i++)
#pragma unroll
                for (int j = 0; j < 2; j++)
                    acc[i][j] = __builtin_amdgcn_mfma_f32_16x16x32_bf16(af[i], bfr[j], acc[i][j], 0, 0, 0);
        }
        if (t + 1 < nk) {
            const int nb = cb ^ 1;
            *(us8*)&As[nb][sar][sac] = a0;
            if (BM == 64) *(us8*)&As[nb][sar][sac + 8] = a1;
            *(us8*)&Bs[nb][sbr][sbc] = b0;
            *(us8*)&Bs[nb][sbr][sbc + 8] = b1;
            __syncthreads();
        }
    }

#pragma unroll
    for (int j = 0; j < 2; j++) {
        int n = bn + wc + j * 16 + lm;
        float bv = bias[n];
        float dv = 0.f;
        if (PE == 1) dv = expf((float)(n & ~1) * (-9.210340371976184f / (float)DM));
#pragma unroll
        for (int i = 0; i < MI; i++) {
#pragma unroll
            for (int r = 0; r < 4; r++) {
                int m = bm + wr + i * 16 + quad * 4 + r;
                float v = (acc[i][j][r] + bv) * alpha;
                if (PE == 1) {
                    float ang = (float)(m & (SEQ - 1)) * dv;
                    v += (n & 1) ? cosf(ang) : sinf(ang);
                }
                if (PE == 2) { if (n & 1) v += 1.f; }
                if (RELU) v = fmaxf(v, 0.f);
                size_t off = (size_t)m * N + n;
                if (resid) v += b2f(resid[off]);
                if (OUTF32) ((float*)Cv)[off] = v;
                else        ((u16*)Cv)[off]  = f2b(v);
            }
        }
    }
}

// ============ MFMA GEMM, 64x128 tile, BK=64, dbuf — for mid-size N%128 GEMMs ============
template <int RELU>
__global__ __launch_bounds__(256) void mgemm128_k(
    const u16* __restrict__ A, const u16* __restrict__ W,
    const float* __restrict__ bias, u16* __restrict__ C,
    int M, int N, int K)
{
    __shared__ u16 As[2][64][72];
    __shared__ u16 Bs[2][128][72];
    const int bm = blockIdx.y * 64, bn = blockIdx.x * 128;
    const int tid = threadIdx.x;
    const int wave = tid >> 6, lane = tid & 63;
    const int wr = (wave >> 1) * 32, wc = (wave & 1) * 64;
    const int lm = lane & 15, quad = lane >> 4;
    const int sar = tid >> 2, sac = (tid & 3) * 16;
    const int sbr = tid >> 1, sbc = (tid & 1) * 32;

    const u16* Arow = A + (size_t)(bm + sar) * K + sac;
    const u16* Wrow = W + (size_t)(bn + sbr) * K + sbc;

    us8 a0 = *(const us8*)(Arow);
    us8 a1 = *(const us8*)(Arow + 8);
    us8 b0 = *(const us8*)(Wrow);
    us8 b1 = *(const us8*)(Wrow + 8);
    us8 b2 = *(const us8*)(Wrow + 16);
    us8 b3 = *(const us8*)(Wrow + 24);

    f4 acc[2][4];
#pragma unroll
    for (int i = 0; i < 2; i++)
#pragma unroll
        for (int j = 0; j < 4; j++) acc[i][j] = (f4)(0.f);

    const int nk = K >> 6;
    *(us8*)&As[0][sar][sac]     = a0;
    *(us8*)&As[0][sar][sac + 8] = a1;
    *(us8*)&Bs[0][sbr][sbc]      = b0;
    *(us8*)&Bs[0][sbr][sbc + 8]  = b1;
    *(us8*)&Bs[0][sbr][sbc + 16] = b2;
    *(us8*)&Bs[0][sbr][sbc + 24] = b3;
    __syncthreads();

    for (int t = 0; t < nk; t++) {
        const int cb = t & 1;
        if (t + 1 < nk) {
            int off = (t + 1) << 6;
            a0 = *(const us8*)(Arow + off);
            a1 = *(const us8*)(Arow + off + 8);
            b0 = *(const us8*)(Wrow + off);
            b1 = *(const us8*)(Wrow + off + 8);
            b2 = *(const us8*)(Wrow + off + 16);
            b3 = *(const us8*)(Wrow + off + 24);
        }
#pragma unroll
        for (int ks = 0; ks < 2; ks++) {
            s8 af[2], bfr[4];
#pragma unroll
            for (int i = 0; i < 2; i++) af[i] = *(const s8*)&As[cb][wr + i * 16 + lm][ks * 32 + quad * 8];
#pragma unroll
            for (int j = 0; j < 4; j++) bfr[j] = *(const s8*)&Bs[cb][wc + j * 16 + lm][ks * 32 + quad * 8];
#pragma unroll
            for (int i = 0; i < 2; i++)
#pragma unroll
                for (int j = 0; j < 4; j++)
                    acc[i][j] = __builtin_amdgcn_mfma_f32_16x16x32_bf16(af[i], bfr[j], acc[i][j], 0, 0, 0);
        }
        if (t + 1 < nk) {
            const int nb = cb ^ 1;
            *(us8*)&As[nb][sar][sac]     = a0;
            *(us8*)&As[nb][sar][sac + 8] = a1;
            *(us8*)&Bs[nb][sbr][sbc]      = b0;
            *(us8*)&Bs[nb][sbr][sbc + 8]  = b1;
            *(us8*)&Bs[nb][sbr][sbc + 16] = b2;
            *(us8*)&Bs[nb][sbr][sbc + 24] = b3;
            __syncthreads();
        }
    }

#pragma unroll
    for (int j = 0; j < 4; j++) {
        int n = bn + wc + j * 16 + lm;
        float bv = bias[n];
#pragma unroll
        for (int i = 0; i < 2; i++) {
#pragma unroll
            for (int r = 0; r < 4; r++) {
                int m = bm + wr + i * 16 + quad * 4 + r;
                float v = acc[i][j][r] + bv;
                if (RELU) v = fmaxf(v, 0.f);
                C[(size_t)m * N + n] = f2b(v);
            }
        }
    }
}

// ============ MFMA GEMM, 128x128 tile, BK=32, dbuf — for big GEMMs (grid>=192) ============
// 16 MFMA per wave per barrier; 40 KB LDS -> 4 blocks/CU.
template <int RELU>
__global__ __launch_bounds__(256) void mgemm256_k(
    const u16* __restrict__ A, const u16* __restrict__ W,
    const float* __restrict__ bias, u16* __restrict__ C,
    int M, int N, int K)
{
    __shared__ u16 As[2][128][40];
    __shared__ u16 Bs[2][128][40];
    const int bm = blockIdx.y * 128, bn = blockIdx.x * 128;
    const int tid = threadIdx.x;
    const int wave = tid >> 6, lane = tid & 63;
    const int wr = (wave >> 1) * 64, wc = (wave & 1) * 64;
    const int lm = lane & 15, quad = lane >> 4;
    const int sr = tid >> 1, sc = (tid & 1) * 16;  // 128 rows, 2 thr/row, 16 elems each

    const u16* Arow = A + (size_t)(bm + sr) * K + sc;
    const u16* Wrow = W + (size_t)(bn + sr) * K + sc;

    us8 a0 = *(const us8*)(Arow);
    us8 a1 = *(const us8*)(Arow + 8);
    us8 b0 = *(const us8*)(Wrow);
    us8 b1 = *(const us8*)(Wrow + 8);

    f4 acc[4][4];
#pragma unroll
    for (int i = 0; i < 4; i++)
#pragma unroll
        for (int j = 0; j < 4; j++) acc[i][j] = (f4)(0.f);

    const int nk = K >> 5;
    *(us8*)&As[0][sr][sc]     = a0;
    *(us8*)&As[0][sr][sc + 8] = a1;
    *(us8*)&Bs[0][sr][sc]     = b0;
    *(us8*)&Bs[0][sr][sc + 8] = b1;
    __syncthreads();

    for (int t = 0; t < nk; t++) {
        const int cb = t & 1;
        if (t + 1 < nk) {
            int off = (t + 1) << 5;
            a0 = *(const us8*)(Arow + off);
            a1 = *(const us8*)(Arow + off + 8);
            b0 = *(const us8*)(Wrow + off);
            b1 = *(const us8*)(Wrow + off + 8);
        }
        s8 af[4], bfr[4];
#pragma unroll
        for (int i = 0; i < 4; i++) af[i] = *(const s8*)&As[cb][wr + i * 16 + lm][quad * 8];
#pragma unroll
        for (int j = 0; j < 4; j++) bfr[j] = *(const s8*)&Bs[cb][wc + j * 16 + lm][quad * 8];
#pragma unroll
        for (int i = 0; i < 4; i++)
#pragma unroll
            for (int j = 0; j < 4; j++)
                acc[i][j] = __builtin_amdgcn_mfma_f32_16x16x32_bf16(af[i], bfr[j], acc[i][j], 0, 0, 0);
        if (t + 1 < nk) {
            const int nb = cb ^ 1;
            *(us8*)&As[nb][sr][sc]     = a0;
            *(us8*)&As[nb][sr][sc + 8] = a1;
            *(us8*)&Bs[nb][sr][sc]     = b0;
            *(us8*)&Bs[nb][sr][sc + 8] = b1;
            __syncthreads();
        }
    }

#pragma unroll
    for (int j = 0; j < 4; j++) {
        int n = bn + wc + j * 16 + lm;
        float bv = bias[n];
#pragma unroll
        for (int i = 0; i < 4; i++) {
#pragma unroll
            for (int r = 0; r < 4; r++) {
                int m = bm + wr + i * 16 + quad * 4 + r;
                float v = acc[i][j][r] + bv;
                if (RELU) v = fmaxf(v, 0.f);
                C[(size_t)m * N + n] = f2b(v);
            }
        }
    }
}

// ============ Fused flash attention (verified R8 structure) ============
template <int CAUSAL>
__global__ __launch_bounds__(256) void flash_k(
    const u16* __restrict__ Q, int qs,
    const u16* __restrict__ Kp, int ks,
    const u16* __restrict__ V, int vs,
    u16* __restrict__ O, int Sq, int Sk)
{
    __shared__ u16 Qs[64][72];
    __shared__ u16 Ks[128][72];
    __shared__ u16 Vs[64][136];
    __shared__ u16 Ps[4][16][136];
    const int bm = blockIdx.x * 64;
    const int bh = blockIdx.y, b = bh >> 3, h = bh & 7;
    const int tid = threadIdx.x;
    const int wave = tid >> 6, lane = tid & 63;
    const int lm = lane & 15, quad = lane >> 4;

    const u16* Qb = Q + (size_t)(b * Sq + bm) * qs + h * HD;
    {
        int r = tid >> 2, c = (tid & 3) * 16;
        *(us8*)&Qs[r][c]     = *(const us8*)(Qb + (size_t)r * qs + c);
        *(us8*)&Qs[r][c + 8] = *(const us8*)(Qb + (size_t)r * qs + c + 8);
    }

    float mrow[4], lrow[4];
    f4 o[4];
#pragma unroll
    for (int r = 0; r < 4; r++) { mrow[r] = -1e30f; lrow[r] = 0.f; }
#pragma unroll
    for (int nt = 0; nt < 4; nt++) o[nt] = (f4)(0.f);

    const u16* Kb = Kp + (size_t)(b * Sk) * ks + h * HD;
    const u16* Vb = V + (size_t)(b * Sk) * vs + h * HD;
    int nkt = Sk >> 7;
    if (CAUSAL) { int lim = (bm + 63) / 128 + 1; if (lim < nkt) nkt = lim; }

    const int vd = tid & 63, vkb = tid >> 6;
    const int kr = tid >> 3, kc8 = (tid & 7) * 8;

    for (int kt = 0; kt < nkt; kt++) {
        const u16* Kt = Kb + ((size_t)kt << 7) * ks;
        const u16* Vt = Vb + ((size_t)kt << 7) * vs;
#pragma unroll
        for (int p = 0; p < 4; p++) {
            int r = p * 32 + kr;
            *(us8*)&Ks[r][kc8] = *(const us8*)(Kt + (size_t)r * ks + kc8);
        }
#pragma unroll
        for (int p = 0; p < 32; p++) {
            int kv = p * 4 + vkb;
            Vs[vd][kv] = Vt[(size_t)kv * vs + vd];
        }
        __syncthreads();

        f4 sa[8];
#pragma unroll
        for (int nt = 0; nt < 8; nt++) sa[nt] = (f4)(0.f);
#pragma unroll
        for (int ks2 = 0; ks2 < 2; ks2++) {
            s8 aq = *(const s8*)&Qs[wave * 16 + lm][ks2 * 32 + quad * 8];
#pragma unroll
            for (int nt = 0; nt < 8; nt++) {
                s8 bk = *(const s8*)&Ks[nt * 16 + lm][ks2 * 32 + quad * 8];
                sa[nt] = __builtin_amdgcn_mfma_f32_16x16x32_bf16(aq, bk, sa[nt], 0, 0, 0);
            }
        }
        float tmx[4] = {-1e30f, -1e30f, -1e30f, -1e30f};
#pragma unroll
        for (int nt = 0; nt < 8; nt++) {
#pragma unroll
            for (int r = 0; r < 4; r++) {
                float v = sa[nt][r] * 0.125f;
                if (CAUSAL) {
                    int col = (kt << 7) + nt * 16 + lm;
                    int row = bm + wave * 16 + quad * 4 + r;
                    if (col > row) v = -1e30f;
                }
                sa[nt][r] = v;
                tmx[r] = fmaxf(tmx[r], v);
            }
        }
#pragma unroll
        for (int st = 1; st < 16; st <<= 1)
#pragma unroll
            for (int r = 0; r < 4; r++) tmx[r] = fmaxf(tmx[r], __shfl_xor(tmx[r], st));
        float al[4];
#pragma unroll
        for (int r = 0; r < 4; r++) {
            float mn = fmaxf(mrow[r], tmx[r]);
            al[r] = __expf(mrow[r] - mn);
            mrow[r] = mn;
        }
        float ts[4] = {0.f, 0.f, 0.f, 0.f};
#pragma unroll
        for (int nt = 0; nt < 8; nt++) {
#pragma unroll
            for (int r = 0; r < 4; r++) {
                float pe = __expf(sa[nt][r] - mrow[r]);
                sa[nt][r] = pe;
                ts[r] += pe;
            }
        }
#pragma unroll
        for (int st = 1; st < 16; st <<= 1)
#pragma unroll
            for (int r = 0; r < 4; r++) ts[r] += __shfl_xor(ts[r], st);
#pragma unroll
        for (int r = 0; r < 4; r++) lrow[r] = lrow[r] * al[r] + ts[r];
#pragma unroll
        for (int nt = 0; nt < 4; nt++)
#pragma unroll
            for (int r = 0; r < 4; r++) o[nt][r] *= al[r];
#pragma unroll
        for (int nt = 0; nt < 8; nt++)
#pragma unroll
            for (int r = 0; r < 4; r++)
                Ps[wave][quad * 4 + r][nt * 16 + lm] = f2b(sa[nt][r]);
#pragma unroll
        for (int kc = 0; kc < 4; kc++) {
            s8 ap = *(const s8*)&Ps[wave][lm][kc * 32 + quad * 8];
#pragma unroll
            for (int nt = 0; nt < 4; nt++) {
                s8 bv = *(const s8*)&Vs[nt * 16 + lm][kc * 32 + quad * 8];
                o[nt] = __builtin_amdgcn_mfma_f32_16x16x32_bf16(ap, bv, o[nt], 0, 0, 0);
            }
        }
        __syncthreads();
    }

    float inv[4];
#pragma unroll
    for (int r = 0; r < 4; r++) inv[r] = 1.f / lrow[r];
#pragma unroll
    for (int nt = 0; nt < 4; nt++) {
#pragma unroll
        for (int r = 0; r < 4; r++) {
            int m = bm + wave * 16 + quad * 4 + r;
            O[(size_t)(b * Sq + m) * DM + h * HD + nt * 16 + lm] = f2b(o[nt][r] * inv[r]);
        }
    }
}

// ---------------- layernorm: 1 wave per row of 512, no barriers ----------------
__global__ __launch_bounds__(256) void ln_k(u16* __restrict__ x,
                                            const float* __restrict__ g,
                                            const float* __restrict__ b)
{
    const int wave = threadIdx.x >> 6, lane = threadIdx.x & 63;
    const int row = blockIdx.x * 4 + wave;
    u16* xr = x + (size_t)row * DM + lane * 8;
    us8 v8 = *(const us8*)xr;
    float v[8];
    float s = 0.f;
#pragma unroll
    for (int e = 0; e < 8; e++) { v[e] = b2f(v8[e]); s += v[e]; }
#pragma unroll
    for (int st = 1; st < 64; st <<= 1) s += __shfl_xor(s, st);
    float mean = s * (1.f / DM);
    float q = 0.f;
#pragma unroll
    for (int e = 0; e < 8; e++) { float d = v[e] - mean; q += d * d; }
#pragma unroll
    for (int st = 1; st < 64; st <<= 1) q += __shfl_xor(q, st);
    float rstd = rsqrtf(q * (1.f / DM) + 1e-5f);
    f4 g0 = *(const f4*)(g + lane * 8), g1 = *(const f4*)(g + lane * 8 + 4);
    f4 b0 = *(const f4*)(b + lane * 8), b1 = *(const f4*)(b + lane * 8 + 4);
    us8 o;
#pragma unroll
    for (int e = 0; e < 4; e++) {
        o[e]     = f2b((v[e]     - mean) * rstd * g0[e] + b0[e]);
        o[e + 4] = f2b((v[e + 4] - mean) * rstd * g1[e] + b1[e]);
    }
    *(us8*)xr = o;
}

// ---------------- host orchestration ----------------
static inline dim3 mg64(int M, int N) { return dim3(N / 64, M / 64); }
static inline dim3 mg32(int M, int N) { return dim3(N / 64, M / 32); }
static inline dim3 mg128(int M, int N) { return dim3(N / 128, M / 64); }
static inline dim3 mg256(int M, int N) { return dim3(N / 128, M / 128); }

extern "C" void kernel_launch(void* const* d_in, const int* in_sizes, int n_in,
                              void* d_out, int out_size, void* d_ws, size_t ws_size,
                              hipStream_t stream)
{
    const float* src       = (const float*)d_in[0];
    const float* tgt       = (const float*)d_in[1];
    const float* enc_in_w  = (const float*)d_in[2];
    const float* enc_in_b  = (const float*)d_in[3];
    const float* dec_in_w  = (const float*)d_in[4];
    const float* dec_in_b  = (const float*)d_in[5];
    const float* out_w     = (const float*)d_in[6];
    const float* out_b     = (const float*)d_in[7];
    const float* enc_attn_w = (const float*)d_in[8];
    const float* enc_attn_b = (const float*)d_in[9];
    const float* enc_out_w  = (const float*)d_in[10];
    const float* enc_out_b  = (const float*)d_in[11];
    const float* enc_ff1_w  = (const float*)d_in[12];
    const float* enc_ff1_b  = (const float*)d_in[13];
    const float* enc_ff2_w  = (const float*)d_in[14];
    const float* enc_ff2_b  = (const float*)d_in[15];
    const float* enc_ln1_g  = (const float*)d_in[16];
    const float* enc_ln1_b  = (const float*)d_in[17];
    const float* enc_ln2_g  = (const float*)d_in[18];
    const float* enc_ln2_b  = (const float*)d_in[19];
    const float* dec_sa_w     = (const float*)d_in[20];
    const float* dec_sa_b     = (const float*)d_in[21];
    const float* dec_sa_out_w = (const float*)d_in[22];
    const float* dec_sa_out_b = (const float*)d_in[23];
    const float* dec_ca_w     = (const float*)d_in[24];
    const float* dec_ca_b     = (const float*)d_in[25];
    const float* dec_ca_out_w = (const float*)d_in[26];
    const float* dec_ca_out_b = (const float*)d_in[27];
    const float* dec_ff1_w    = (const float*)d_in[28];
    const float* dec_ff1_b    = (const float*)d_in[29];
    const float* dec_ff2_w    = (const float*)d_in[30];
    const float* dec_ff2_b    = (const float*)d_in[31];
    const float* dec_ln1_g    = (const float*)d_in[32];
    const float* dec_ln1_b    = (const float*)d_in[33];
    const float* dec_ln2_g    = (const float*)d_in[34];
    const float* dec_ln2_b    = (const float*)d_in[35];
    const float* dec_ln3_g    = (const float*)d_in[36];
    const float* dec_ln3_b    = (const float*)d_in[37];

    const int ME = BB * SEQ;  // 2048
    const int MD = BB * TGT;  // 1024
    const int BH = BB * NH;   // 32
    const float SQD = 22.627416997969522f;  // sqrt(512)

    const size_t SZ_ATTN = (size_t)NL * 3 * DM * DM;
    const size_t SZ_OUT  = (size_t)NL * DM * DM;
    const size_t SZ_FF   = (size_t)NL * FFD * DM;

    // ---- workspace layout ----
    float* fp = (float*)d_ws;
    float* kvbias = fp; fp += NL * 2 * DM;
    u16* p = (u16*)fp;
    u16* xa   = p; p += (size_t)ME * DM;
    u16* xb   = p; p += (size_t)ME * DM;
    u16* reg1 = p; p += (size_t)ME * FFD;
    u16* tbuf = p; p += (size_t)ME * DM;
    u16* ya   = p; p += (size_t)MD * DM;
    u16* yb   = p; p += (size_t)MD * DM;
    u16* kvall = p; p += (size_t)ME * NL * 2 * DM;
    u16* src_b     = p; p += (size_t)ME * HD;
    u16* tgt_b     = p; p += (size_t)MD * HD;
    u16* enc_in_wb = p; p += (size_t)DM * HD;
    u16* dec_in_wb = p; p += (size_t)DM * HD;
    u16* out_wb    = p; p += (size_t)HD * DM;
    u16* enc_at_wb = p; p += SZ_ATTN;
    u16* enc_ow_wb = p; p += SZ_OUT;
    u16* enc_f1_wb = p; p += SZ_FF;
    u16* enc_f2_wb = p; p += SZ_FF;
    u16* dec_sa_wb = p; p += SZ_ATTN;
    u16* dec_sao_wb = p; p += SZ_OUT;
    u16* dec_ca_wb = p; p += SZ_ATTN;
    u16* dec_cao_wb = p; p += SZ_OUT;
    u16* dec_f1_wb = p; p += SZ_FF;
    u16* dec_f2_wb = p; p += SZ_FF;
    u16* kvstack   = p; p += (size_t)NL * 2 * DM * DM;

    // ===== single batched cast (21 segments, 8 elems/thread, nontemporal) =====
    CastSegs cs;
    int ns = 0;
    auto seg = [&](const float* s, u16* d, size_t n) {
        cs.src[ns] = s; cs.dst[ns] = d;
        cs.cum[ns + 1] = cs.cum[ns] + (int)(n / 8);
        ns++;
    };
    cs.cum[0] = 0;
    seg(src,          src_b,     (size_t)ME * HD);
    seg(tgt,          tgt_b,     (size_t)MD * HD);
    seg(enc_in_w,     enc_in_wb, (size_t)DM * HD);
    seg(dec_in_w,     dec_in_wb, (size_t)DM * HD);
    seg(out_w,        out_wb,    (size_t)HD * DM);
    seg(enc_attn_w,   enc_at_wb, SZ_ATTN);
    seg(enc_out_w,    enc_ow_wb, SZ_OUT);
    seg(enc_ff1_w,    enc_f1_wb, SZ_FF);
    seg(enc_ff2_w,    enc_f2_wb, SZ_FF);
    seg(dec_sa_w,     dec_sa_wb, SZ_ATTN);
    seg(dec_sa_out_w, dec_sao_wb, SZ_OUT);
    seg(dec_ca_w,     dec_ca_wb, SZ_ATTN);
    seg(dec_ca_out_w, dec_cao_wb, SZ_OUT);
    seg(dec_ff1_w,    dec_f1_wb, SZ_FF);
    seg(dec_ff2_w,    dec_f2_wb, SZ_FF);
    for (int i = 0; i < NL; i++)
        seg(dec_ca_w + (size_t)i * 3 * DM * DM + (size_t)DM * DM,
            kvstack + (size_t)i * 2 * DM * DM, (size_t)2 * DM * DM);
    cs.nseg = ns;
    castseg_k<<<(cs.cum[ns] + 255) / 256, 256, 0, stream>>>(cs);
    kvbias_k<<<(NL * 2 * DM + 255) / 256, 256, 0, stream>>>(dec_ca_b, kvbias);

    // ===== encoder =====
    mgemm_k<0, 0, 64, 1><<<mg64(ME, DM), 256, 0, stream>>>(src_b, enc_in_wb, enc_in_b, nullptr, xa, ME, DM, HD, SQD);

    u16* cur = xa; u16* alt = xb;
    for (int i = 0; i < NL; i++) {
        const u16* W = enc_at_wb + (size_t)i * 3 * DM * DM;
        const float* Bw = enc_attn_b + (size_t)i * 3 * DM;
        mgemm256_k<0><<<mg256(ME, 3 * DM), 256, 0, stream>>>(cur, W, Bw, reg1, ME, 3 * DM, DM);
        flash_k<0><<<dim3(SEQ / 64, BH), 256, 0, stream>>>(reg1, 3 * DM, reg1 + DM, 3 * DM, reg1 + 2 * DM, 3 * DM, tbuf, SEQ, SEQ);
        mgemm_k<0, 0, 32, 0><<<mg32(ME, DM), 256, 0, stream>>>(tbuf, enc_ow_wb + (size_t)i * DM * DM, enc_out_b + (size_t)i * DM, cur, alt, ME, DM, DM, 1.f);
        ln_k<<<ME / 4, 256, 0, stream>>>(alt, enc_ln1_g + (size_t)i * DM, enc_ln1_b + (size_t)i * DM);
        { u16* t = cur; cur = alt; alt = t; }
        mgemm256_k<1><<<mg256(ME, FFD), 256, 0, stream>>>(cur, enc_f1_wb + (size_t)i * FFD * DM, enc_ff1_b + (size_t)i * FFD, reg1, ME, FFD, DM);
        mgemm_k<0, 0, 32, 0><<<mg32(ME, DM), 256, 0, stream>>>(reg1, enc_f2_wb + (size_t)i * DM * FFD, enc_ff2_b + (size_t)i * DM, cur, alt, ME, DM, FFD, 1.f);
        ln_k<<<ME / 4, 256, 0, stream>>>(alt, enc_ln2_g + (size_t)i * DM, enc_ln2_b + (size_t)i * DM);
        { u16* t = cur; cur = alt; alt = t; }
    }
    u16* mem = cur;  // xa (even swaps)

    // ===== all 6 layers' cross-attn K/V projections in one GEMM =====
    mgemm256_k<0><<<mg256(ME, NL * 2 * DM), 256, 0, stream>>>(mem, kvstack, kvbias, kvall, ME, NL * 2 * DM, DM);

    // ===== decoder =====
    mgemm_k<0, 0, 32, 2><<<mg32(MD, DM), 256, 0, stream>>>(tgt_b, dec_in_wb, dec_in_b, nullptr, ya, MD, DM, HD, SQD);

    u16* dc = ya; u16* da = yb;
    for (int i = 0; i < NL; i++) {
        // --- self-attention (causal), fused QKV ---
        const u16* W = dec_sa_wb + (size_t)i * 3 * DM * DM;
        const float* Bw = dec_sa_b + (size_t)i * 3 * DM;
        mgemm128_k<0><<<mg128(MD, 3 * DM), 256, 0, stream>>>(dc, W, Bw, reg1, MD, 3 * DM, DM);
        flash_k<1><<<dim3(TGT / 64, BH), 256, 0, stream>>>(reg1, 3 * DM, reg1 + DM, 3 * DM, reg1 + 2 * DM, 3 * DM, tbuf, TGT, TGT);
        mgemm_k<0, 0, 32, 0><<<mg32(MD, DM), 256, 0, stream>>>(tbuf, dec_sao_wb + (size_t)i * DM * DM, dec_sa_out_b + (size_t)i * DM, dc, da, MD, DM, DM, 1.f);
        ln_k<<<MD / 4, 256, 0, stream>>>(da, dec_ln1_g + (size_t)i * DM, dec_ln1_b + (size_t)i * DM);
        { u16* t = dc; dc = da; da = t; }

        // --- cross-attention (K/V precomputed in kvall) ---
        const u16* Wc = dec_ca_wb + (size_t)i * 3 * DM * DM;
        const float* Bc = dec_ca_b + (size_t)i * 3 * DM;
        u16* qbuf = reg1;
        mgemm_k<0, 0, 32, 0><<<mg32(MD, DM), 256, 0, stream>>>(dc, Wc, Bc, nullptr, qbuf, MD, DM, DM, 1.f);
        const u16* kvl = kvall + (size_t)i * 2 * DM;
        flash_k<0><<<dim3(TGT / 64, BH), 256, 0, stream>>>(qbuf, DM, kvl, NL * 2 * DM, kvl + DM, NL * 2 * DM, tbuf, TGT, SEQ);
        mgemm_k<0, 0, 32, 0><<<mg32(MD, DM), 256, 0, stream>>>(tbuf, dec_cao_wb + (size_t)i * DM * DM, dec_ca_out_b + (size_t)i * DM, dc, da, MD, DM, DM, 1.f);
        ln_k<<<MD / 4, 256, 0, stream>>>(da, dec_ln2_g + (size_t)i * DM, dec_ln2_b + (size_t)i * DM);
        { u16* t = dc; dc = da; da = t; }

        // --- feed-forward ---
        mgemm128_k<1><<<mg128(MD, FFD), 256, 0, stream>>>(dc, dec_f1_wb + (size_t)i * FFD * DM, dec_ff1_b + (size_t)i * FFD, reg1, MD, FFD, DM);
        mgemm_k<0, 0, 32, 0><<<mg32(MD, DM), 256, 0, stream>>>(reg1, dec_f2_wb + (size_t)i * DM * FFD, dec_ff2_b + (size_t)i * DM, dc, da, MD, DM, FFD, 1.f);
        ln_k<<<MD / 4, 256, 0, stream>>>(da, dec_ln3_g + (size_t)i * DM, dec_ln3_b + (size_t)i * DM);
        { u16* t = dc; dc = da; da = t; }
    }

    // ===== final projection (N=64, fp32 into d_out) =====
    mgemm_k<0, 1, 32, 0><<<mg32(MD, HD), 256, 0, stream>>>(dc, out_wb, out_b, nullptr, (float*)d_out, MD, HD, DM, 1.f);
}